// Round 6
// baseline (294.056 us; speedup 1.0000x reference)
//
#include <hip/hip_runtime.h>
#include <hip/hip_fp16.h>

typedef _Float16 f16x8 __attribute__((ext_vector_type(8)));
typedef float f32x4 __attribute__((ext_vector_type(4)));

#define NPB 256      // nodes per bucket (dst >> 8)
#define FCHUNK 6144  // edges per fill block (24 per thread)
#define MAXBK 512    // LDS bucket array size (>= NBUCK=391)

// x fp32 -> fp16
__global__ void k_xhalf(const float4* __restrict__ x4, __half2* __restrict__ xh2, int n4) {
  int i = blockIdx.x * blockDim.x + threadIdx.x;
  if (i < n4) {
    float4 v = x4[i];
    __half2 a, b;
    a.x = __float2half_rn(v.x); a.y = __float2half_rn(v.y);
    b.x = __float2half_rn(v.z); b.y = __float2half_rn(v.w);
    xh2[2 * i] = a;
    xh2[2 * i + 1] = b;
  }
}

// global per-bucket histogram (block-local LDS first, one flush per bucket)
__global__ void k_hist(const int* __restrict__ dst, int* __restrict__ bins,
                       int E, int chunk) {
  __shared__ int lh[MAXBK];
  for (int i = threadIdx.x; i < MAXBK; i += blockDim.x) lh[i] = 0;
  __syncthreads();
  int e0 = blockIdx.x * chunk;
  int e1 = min(e0 + chunk, E);
  for (int e = e0 + threadIdx.x; e < e1; e += blockDim.x)
    atomicAdd(&lh[dst[e] >> 8], 1);
  __syncthreads();
  for (int i = threadIdx.x; i < MAXBK; i += blockDim.x)
    if (lh[i]) atomicAdd(&bins[i], lh[i]);
}

// exclusive scan of nb bins (nb <= 4096), writes binoff (+sentinel) and cursors
__global__ void k_scan1(const int* __restrict__ bins, int* __restrict__ binoff,
                        int* __restrict__ cur, int nb, int E) {
  __shared__ int lds[1024];
  int t = threadIdx.x;
  int g0 = t * 4;
  int v[4]; int s = 0;
  for (int i = 0; i < 4; ++i) { int idx = g0 + i; v[i] = (idx < nb) ? bins[idx] : 0; s += v[i]; }
  lds[t] = s;
  __syncthreads();
  for (int d = 1; d < 1024; d <<= 1) {
    int a = (t >= d) ? lds[t - d] : 0;
    __syncthreads();
    lds[t] += a;
    __syncthreads();
  }
  int ex = lds[t] - s;
  for (int i = 0; i < 4; ++i) {
    int idx = g0 + i;
    if (idx < nb) { binoff[idx] = ex; cur[idx] = ex; }
    ex += v[i];
  }
  if (t == 0) binoff[nb] = E;
}

// scatter edges into bucket segments with per-(block,bucket) reservation:
// LDS hist -> one global atomic per bucket -> direct scatter via LDS cursors.
__global__ __launch_bounds__(256) void k_fill3(const int* __restrict__ src,
    const int* __restrict__ dst, int* __restrict__ cur,
    int* __restrict__ packed, int E) {
  __shared__ int lh[MAXBK];
  __shared__ int gbase[MAXBK];
  int t = threadIdx.x;
  int e0 = blockIdx.x * FCHUNK;
  int e1 = min(e0 + FCHUNK, E);
  for (int i = t; i < MAXBK; i += 256) lh[i] = 0;
  __syncthreads();
  int dv[24];
#pragma unroll
  for (int i = 0; i < 24; ++i) {
    int e = e0 + t + i * 256;
    dv[i] = (e < e1) ? dst[e] : -1;
    if (dv[i] >= 0) atomicAdd(&lh[dv[i] >> 8], 1);
  }
  __syncthreads();
  for (int i = t; i < MAXBK; i += 256) {
    int c = lh[i];
    gbase[i] = c ? atomicAdd(&cur[i], c) : 0;
    lh[i] = 0;  // reuse as local cursor
  }
  __syncthreads();
#pragma unroll
  for (int i = 0; i < 24; ++i) {
    int d = dv[i];
    if (d >= 0) {
      int e = e0 + t + i * 256;
      int bk = d >> 8;
      int lp = atomicAdd(&lh[bk], 1);
      packed[gbase[bk] + lp] = src[e] | ((d & 255) << 20);
    }
  }
}

// per-bucket counting sort: bucket segment -> per-node CSR (+ offA, deg)
__global__ __launch_bounds__(256) void k_sort(const int* __restrict__ packed,
    const int* __restrict__ binoff, int* __restrict__ csr,
    int* __restrict__ offA, int* __restrict__ deg, int N) {
  __shared__ int hist[NPB];
  __shared__ int sc[NPB];
  __shared__ int curs[NPB];
  int b = blockIdx.x, t = threadIdx.x;
  hist[t] = 0;
  __syncthreads();
  int e0 = binoff[b], e1 = binoff[b + 1];
  for (int e = e0 + t; e < e1; e += 256)
    atomicAdd(&hist[(packed[e] >> 20) & 255], 1);
  __syncthreads();
  int v = hist[t];
  sc[t] = v;
  __syncthreads();
  for (int d = 1; d < 256; d <<= 1) {
    int a = (t >= d) ? sc[t - d] : 0;
    __syncthreads();
    sc[t] += a;
    __syncthreads();
  }
  int ex = e0 + sc[t] - v;   // global CSR start for this node
  curs[t] = ex;
  int n = b * NPB + t;
  if (n < N) { offA[n] = ex; deg[n] = v; }
  __syncthreads();
  for (int e = e0 + t; e < e1; e += 256) {
    int pk = packed[e];
    int p = atomicAdd(&curs[(pk >> 20) & 255], 1);
    csr[p] = pk & 0xFFFFF;
  }
}

// S[n] = sum over incoming edges of x[src] (fp16 gather, fp32 reg accumulate, fp16 out)
__global__ void k_agg(const __half* __restrict__ xh, const int* __restrict__ offA,
                      const int* __restrict__ deg, const int* __restrict__ csr,
                      __half* __restrict__ Sh, int N) {
  int lane = threadIdx.x & 63;
  int wid = (blockIdx.x * blockDim.x + threadIdx.x) >> 6;
  int nw = (gridDim.x * blockDim.x) >> 6;
  for (int n = wid; n < N; n += nw) {
    int j0 = offA[n], dg = deg[n];
    float acc = 0.f;
    int j = 0;
    for (; j + 8 <= dg; j += 8) {
      int s0 = csr[j0 + j],     s1 = csr[j0 + j + 1];
      int s2 = csr[j0 + j + 2], s3 = csr[j0 + j + 3];
      int s4 = csr[j0 + j + 4], s5 = csr[j0 + j + 5];
      int s6 = csr[j0 + j + 6], s7 = csr[j0 + j + 7];
      float v0 = __half2float(xh[(size_t)s0 * 64 + lane]);
      float v1 = __half2float(xh[(size_t)s1 * 64 + lane]);
      float v2 = __half2float(xh[(size_t)s2 * 64 + lane]);
      float v3 = __half2float(xh[(size_t)s3 * 64 + lane]);
      float v4 = __half2float(xh[(size_t)s4 * 64 + lane]);
      float v5 = __half2float(xh[(size_t)s5 * 64 + lane]);
      float v6 = __half2float(xh[(size_t)s6 * 64 + lane]);
      float v7 = __half2float(xh[(size_t)s7 * 64 + lane]);
      acc += ((v0 + v1) + (v2 + v3)) + ((v4 + v5) + (v6 + v7));
    }
    for (; j + 4 <= dg; j += 4) {
      int s0 = csr[j0 + j], s1 = csr[j0 + j + 1], s2 = csr[j0 + j + 2], s3 = csr[j0 + j + 3];
      float v0 = __half2float(xh[(size_t)s0 * 64 + lane]);
      float v1 = __half2float(xh[(size_t)s1 * 64 + lane]);
      float v2 = __half2float(xh[(size_t)s2 * 64 + lane]);
      float v3 = __half2float(xh[(size_t)s3 * 64 + lane]);
      acc += (v0 + v1) + (v2 + v3);
    }
    for (; j < dg; ++j) {
      int s = csr[j0 + j];
      acc += __half2float(xh[(size_t)s * 64 + lane]);
    }
    Sh[(size_t)n * 64 + lane] = __float2half_rn(acc);
  }
}

// build fp16 B-fragments for the 3 64x64 matrices + c2
// frag f = mat*8 + kk*4 + ct; entry t = lane*8+j holds M[kk*32+(lane>>4)*8+j][ct*16+(lane&15)]
__global__ void k_mats2(const float* __restrict__ We, const float* __restrict__ be,
                        const float* __restrict__ Wn, __half* __restrict__ Wfrag,
                        float* __restrict__ c2) {
  int b = blockIdx.x, t = threadIdx.x;
  if (b < 24) {
    int mat = b >> 3, kk = (b >> 2) & 1, ct = b & 3;
    int lane = t >> 3, j = t & 7;
    int k = kk * 32 + ((lane >> 4) & 3) * 8 + j;
    int col = ct * 16 + (lane & 15);
    float v;
    if (mat == 0) {
      v = Wn[k * 64 + col];
    } else if (mat == 1) {
      float a = 0.f;
      for (int m = 0; m < 64; ++m) a += We[k * 64 + m] * Wn[(64 + m) * 64 + col];
      v = a;
    } else {
      float a = 0.f;
      for (int m = 0; m < 64; ++m) a += We[(64 + k) * 64 + m] * Wn[(64 + m) * 64 + col];
      v = a;
    }
    Wfrag[b * 512 + t] = __float2half_rn(v);
  } else if (t < 64) {
    float a = 0.f;
    for (int m = 0; m < 64; ++m) a += be[m] * Wn[(64 + m) * 64 + t];
    c2[t] = a;
  }
}

// node model via MFMA: h = PReLU(x@M1 + S@M2 + deg*(x@M3 + c2) + b); h -> fp16
// ONE 16-row tile per wave: grid sized so wid covers ntile (max TLP, no serial chain)
__global__ __launch_bounds__(256) void k_nodeM(const __half* __restrict__ xh,
    const __half* __restrict__ Sh, const int* __restrict__ deg,
    const __half* __restrict__ Wfrag, const float* __restrict__ c2,
    const float* __restrict__ bnode, const float* __restrict__ pa,
    __half* __restrict__ Hh, float* __restrict__ stats, int N) {
  const f16x8* WF = (const f16x8*)Wfrag;
  int t = threadIdx.x, lane = t & 63;
  f16x8 B[24];
#pragma unroll
  for (int f = 0; f < 24; ++f) B[f] = WF[f * 64 + lane];
  float slope = pa[0];
  int wid = (blockIdx.x * blockDim.x + t) >> 6;
  int nw = (gridDim.x * blockDim.x) >> 6;
  int ntile = N >> 4;
  int r = lane & 15, g = lane >> 4;
  float ws[4] = {0, 0, 0, 0}, wq[4] = {0, 0, 0, 0};
  for (int tile = wid; tile < ntile; tile += nw) {
    int n0 = tile << 4;
    // issue deg loads early so they overlap the MFMA chains
    float dg[4];
#pragma unroll
    for (int q = 0; q < 4; ++q) dg[q] = (float)deg[n0 + g * 4 + q];
    const f16x8* xp = (const f16x8*)(xh + (size_t)(n0 + r) * 64 + g * 8);
    const f16x8* sp = (const f16x8*)(Sh + (size_t)(n0 + r) * 64 + g * 8);
    f16x8 ax0 = xp[0], ax1 = xp[4];
    f16x8 as0 = sp[0], as1 = sp[4];
    f32x4 accA[4], accB[4];
#pragma unroll
    for (int ct = 0; ct < 4; ++ct) {
      f32x4 a = {0.f, 0.f, 0.f, 0.f};
      a = __builtin_amdgcn_mfma_f32_16x16x32_f16(ax0, B[0 + ct], a, 0, 0, 0);
      a = __builtin_amdgcn_mfma_f32_16x16x32_f16(ax1, B[4 + ct], a, 0, 0, 0);
      a = __builtin_amdgcn_mfma_f32_16x16x32_f16(as0, B[8 + ct], a, 0, 0, 0);
      a = __builtin_amdgcn_mfma_f32_16x16x32_f16(as1, B[12 + ct], a, 0, 0, 0);
      accA[ct] = a;
      f32x4 bb = {0.f, 0.f, 0.f, 0.f};
      bb = __builtin_amdgcn_mfma_f32_16x16x32_f16(ax0, B[16 + ct], bb, 0, 0, 0);
      bb = __builtin_amdgcn_mfma_f32_16x16x32_f16(ax1, B[20 + ct], bb, 0, 0, 0);
      accB[ct] = bb;
    }
#pragma unroll
    for (int ct = 0; ct < 4; ++ct) {
      int c = ct * 16 + r;
      float cc = c2[c], bv = bnode[c];
#pragma unroll
      for (int q = 0; q < 4; ++q) {
        float hv = accA[ct][q] + dg[q] * (accB[ct][q] + cc) + bv;
        hv = hv >= 0.f ? hv : slope * hv;
        ws[ct] += hv; wq[ct] += hv * hv;
        Hh[(size_t)(n0 + g * 4 + q) * 64 + c] = __float2half_rn(hv);
      }
    }
  }
#pragma unroll
  for (int ct = 0; ct < 4; ++ct) {
    float s = ws[ct], q = wq[ct];
    s += __shfl_xor(s, 16); q += __shfl_xor(q, 16);
    s += __shfl_xor(s, 32); q += __shfl_xor(q, 32);
    if (lane < 16) {
      int c = ct * 16 + lane;
      atomicAdd(&stats[c], s);
      atomicAdd(&stats[64 + c], q);
    }
  }
}

__global__ void k_bnfinal(const float* __restrict__ stats, const float* __restrict__ gamma,
                          const float* __restrict__ beta, float* __restrict__ ss, int N) {
  int o = threadIdx.x;
  if (o < 64) {
    float fn = (float)N;
    float mean = stats[o] / fn;
    float var = stats[64 + o] / fn - mean * mean;
    float inv = rsqrtf(var + 1e-5f);
    float sc = gamma[o] * inv;
    ss[o] = sc;
    ss[64 + o] = beta[o] - mean * sc;
  }
}

__global__ void k_out2(const __half2* __restrict__ hh, const float* __restrict__ ss,
                       float2* __restrict__ out2, int n2) {
  int i = blockIdx.x * blockDim.x + threadIdx.x;
  if (i < n2) {
    int cb = (i & 31) * 2;
    __half2 v = hh[i];
    float2 o;
    o.x = __half2float(v.x) * ss[cb] + ss[64 + cb];
    o.y = __half2float(v.y) * ss[cb + 1] + ss[64 + cb + 1];
    out2[i] = o;
  }
}

// ---------------- launch ----------------

extern "C" void kernel_launch(void* const* d_in, const int* in_sizes, int n_in,
                              void* d_out, int out_size, void* d_ws, size_t ws_size,
                              hipStream_t stream) {
  const float* x     = (const float*)d_in[0];
  const int*   ei    = (const int*)d_in[1];
  const float* We    = (const float*)d_in[2];
  const float* be    = (const float*)d_in[3];
  const float* Wn    = (const float*)d_in[4];
  const float* bnode = (const float*)d_in[5];
  const float* pa    = (const float*)d_in[6];
  const float* gamma = (const float*)d_in[7];
  const float* beta  = (const float*)d_in[8];

  int N = in_sizes[0] / 64;
  int E = in_sizes[1] / 2;
  const int* srcA = ei;
  const int* dstA = ei + E;

  int NBUCK = (N + NPB - 1) / NPB;     // 391

  char* ws = (char*)d_ws;
  size_t off = 0;
  auto alloc = [&](size_t bytes) -> void* {
    void* p = (void*)(ws + off);
    off += (bytes + 255) & ~(size_t)255;
    return p;
  };
  int*    bins   = (int*)alloc((size_t)NBUCK * 4);
  int*    binoff = (int*)alloc((size_t)(NBUCK + 1) * 4);
  int*    cur    = (int*)alloc((size_t)NBUCK * 4);
  int*    packed = (int*)alloc((size_t)E * 4);
  int*    csr    = (int*)alloc((size_t)E * 4);
  int*    offA   = (int*)alloc((size_t)N * 4);
  int*    deg    = (int*)alloc((size_t)N * 4);
  __half* xh     = (__half*)alloc((size_t)N * 64 * 2);
  __half* Sh     = (__half*)alloc((size_t)N * 64 * 2);
  __half* Hh     = (__half*)alloc((size_t)N * 64 * 2);
  __half* Wfrag  = (__half*)alloc((size_t)24 * 512 * 2);
  float*  c2     = (float*)alloc(64 * 4);
  float*  stats  = (float*)alloc(128 * 4);
  float*  ssbuf  = (float*)alloc(128 * 4);

  hipMemsetAsync(bins, 0, (size_t)NBUCK * 4, stream);
  hipMemsetAsync(stats, 0, 128 * 4, stream);

  int FGRID = (E + FCHUNK - 1) / FCHUNK;   // 261
  int n4 = N * 16;
  int vgrid = (n4 + 255) / 256;
  int n2 = N * 32;
  int ntile = N / 16;                       // 6250
  int mgrid = (ntile + 3) / 4;              // 1563 blocks -> 1 tile per wave

  k_hist<<<FGRID, 256, 0, stream>>>(dstA, bins, E, FCHUNK);
  k_scan1<<<1, 1024, 0, stream>>>(bins, binoff, cur, NBUCK, E);
  k_fill3<<<FGRID, 256, 0, stream>>>(srcA, dstA, cur, packed, E);
  k_sort<<<NBUCK, 256, 0, stream>>>(packed, binoff, csr, offA, deg, N);
  k_xhalf<<<vgrid, 256, 0, stream>>>((const float4*)x, (__half2*)xh, n4);
  k_mats2<<<25, 512, 0, stream>>>(We, be, Wn, Wfrag, c2);
  k_agg<<<2048, 256, 0, stream>>>(xh, offA, deg, csr, Sh, N);
  k_nodeM<<<mgrid, 256, 0, stream>>>(xh, Sh, deg, Wfrag, c2, bnode, pa, Hh, stats, N);
  k_bnfinal<<<1, 64, 0, stream>>>(stats, gamma, beta, ssbuf, N);
  k_out2<<<(n2 + 255) / 256, 256, 0, stream>>>((const __half2*)Hh, ssbuf, (float2*)d_out, n2);
}

// Round 7
// 167.784 us; speedup vs baseline: 1.7526x; 1.7526x over previous
//
#include <hip/hip_runtime.h>
#include <hip/hip_fp16.h>

typedef _Float16 f16x8 __attribute__((ext_vector_type(8)));
typedef float f32x4 __attribute__((ext_vector_type(4)));

#define NPB 256      // nodes per bucket (dst >> 8)
#define FCHUNK 6144  // edges per fill block (24 per thread)
#define MAXBK 512    // LDS bucket array size (>= NBUCK=391)

// x fp32 -> fp16
__global__ void k_xhalf(const float4* __restrict__ x4, __half2* __restrict__ xh2, int n4) {
  int i = blockIdx.x * blockDim.x + threadIdx.x;
  if (i < n4) {
    float4 v = x4[i];
    __half2 a, b;
    a.x = __float2half_rn(v.x); a.y = __float2half_rn(v.y);
    b.x = __float2half_rn(v.z); b.y = __float2half_rn(v.w);
    xh2[2 * i] = a;
    xh2[2 * i + 1] = b;
  }
}

// global per-bucket histogram (block-local LDS first, one flush per bucket)
__global__ void k_hist(const int* __restrict__ dst, int* __restrict__ bins,
                       int E, int chunk) {
  __shared__ int lh[MAXBK];
  for (int i = threadIdx.x; i < MAXBK; i += blockDim.x) lh[i] = 0;
  __syncthreads();
  int e0 = blockIdx.x * chunk;
  int e1 = min(e0 + chunk, E);
  for (int e = e0 + threadIdx.x; e < e1; e += blockDim.x)
    atomicAdd(&lh[dst[e] >> 8], 1);
  __syncthreads();
  for (int i = threadIdx.x; i < MAXBK; i += blockDim.x)
    if (lh[i]) atomicAdd(&bins[i], lh[i]);
}

// exclusive scan of nb bins (nb <= 4096), writes binoff (+sentinel) and cursors
__global__ void k_scan1(const int* __restrict__ bins, int* __restrict__ binoff,
                        int* __restrict__ cur, int nb, int E) {
  __shared__ int lds[1024];
  int t = threadIdx.x;
  int g0 = t * 4;
  int v[4]; int s = 0;
  for (int i = 0; i < 4; ++i) { int idx = g0 + i; v[i] = (idx < nb) ? bins[idx] : 0; s += v[i]; }
  lds[t] = s;
  __syncthreads();
  for (int d = 1; d < 1024; d <<= 1) {
    int a = (t >= d) ? lds[t - d] : 0;
    __syncthreads();
    lds[t] += a;
    __syncthreads();
  }
  int ex = lds[t] - s;
  for (int i = 0; i < 4; ++i) {
    int idx = g0 + i;
    if (idx < nb) { binoff[idx] = ex; cur[idx] = ex; }
    ex += v[i];
  }
  if (t == 0) binoff[nb] = E;
}

// scatter edges into bucket segments with per-(block,bucket) reservation:
// LDS hist -> one global atomic per bucket -> direct scatter via LDS cursors.
__global__ __launch_bounds__(256) void k_fill3(const int* __restrict__ src,
    const int* __restrict__ dst, int* __restrict__ cur,
    int* __restrict__ packed, int E) {
  __shared__ int lh[MAXBK];
  __shared__ int gbase[MAXBK];
  int t = threadIdx.x;
  int e0 = blockIdx.x * FCHUNK;
  int e1 = min(e0 + FCHUNK, E);
  for (int i = t; i < MAXBK; i += 256) lh[i] = 0;
  __syncthreads();
  int dv[24];
#pragma unroll
  for (int i = 0; i < 24; ++i) {
    int e = e0 + t + i * 256;
    dv[i] = (e < e1) ? dst[e] : -1;
    if (dv[i] >= 0) atomicAdd(&lh[dv[i] >> 8], 1);
  }
  __syncthreads();
  for (int i = t; i < MAXBK; i += 256) {
    int c = lh[i];
    gbase[i] = c ? atomicAdd(&cur[i], c) : 0;
    lh[i] = 0;  // reuse as local cursor
  }
  __syncthreads();
#pragma unroll
  for (int i = 0; i < 24; ++i) {
    int d = dv[i];
    if (d >= 0) {
      int e = e0 + t + i * 256;
      int bk = d >> 8;
      int lp = atomicAdd(&lh[bk], 1);
      packed[gbase[bk] + lp] = src[e] | ((d & 255) << 20);
    }
  }
}

// per-bucket counting sort: bucket segment -> per-node CSR (+ offA, deg)
__global__ __launch_bounds__(256) void k_sort(const int* __restrict__ packed,
    const int* __restrict__ binoff, int* __restrict__ csr,
    int* __restrict__ offA, int* __restrict__ deg, int N) {
  __shared__ int hist[NPB];
  __shared__ int sc[NPB];
  __shared__ int curs[NPB];
  int b = blockIdx.x, t = threadIdx.x;
  hist[t] = 0;
  __syncthreads();
  int e0 = binoff[b], e1 = binoff[b + 1];
  for (int e = e0 + t; e < e1; e += 256)
    atomicAdd(&hist[(packed[e] >> 20) & 255], 1);
  __syncthreads();
  int v = hist[t];
  sc[t] = v;
  __syncthreads();
  for (int d = 1; d < 256; d <<= 1) {
    int a = (t >= d) ? sc[t - d] : 0;
    __syncthreads();
    sc[t] += a;
    __syncthreads();
  }
  int ex = e0 + sc[t] - v;   // global CSR start for this node
  curs[t] = ex;
  int n = b * NPB + t;
  if (n < N) { offA[n] = ex; deg[n] = v; }
  __syncthreads();
  for (int e = e0 + t; e < e1; e += 256) {
    int pk = packed[e];
    int p = atomicAdd(&curs[(pk >> 20) & 255], 1);
    csr[p] = pk & 0xFFFFF;
  }
}

// S[n] = sum over incoming edges of x[src] (fp16 gather, fp32 reg accumulate, fp16 out)
__global__ void k_agg(const __half* __restrict__ xh, const int* __restrict__ offA,
                      const int* __restrict__ deg, const int* __restrict__ csr,
                      __half* __restrict__ Sh, int N) {
  int lane = threadIdx.x & 63;
  int wid = (blockIdx.x * blockDim.x + threadIdx.x) >> 6;
  int nw = (gridDim.x * blockDim.x) >> 6;
  for (int n = wid; n < N; n += nw) {
    int j0 = offA[n], dg = deg[n];
    float acc = 0.f;
    int j = 0;
    for (; j + 8 <= dg; j += 8) {
      int s0 = csr[j0 + j],     s1 = csr[j0 + j + 1];
      int s2 = csr[j0 + j + 2], s3 = csr[j0 + j + 3];
      int s4 = csr[j0 + j + 4], s5 = csr[j0 + j + 5];
      int s6 = csr[j0 + j + 6], s7 = csr[j0 + j + 7];
      float v0 = __half2float(xh[(size_t)s0 * 64 + lane]);
      float v1 = __half2float(xh[(size_t)s1 * 64 + lane]);
      float v2 = __half2float(xh[(size_t)s2 * 64 + lane]);
      float v3 = __half2float(xh[(size_t)s3 * 64 + lane]);
      float v4 = __half2float(xh[(size_t)s4 * 64 + lane]);
      float v5 = __half2float(xh[(size_t)s5 * 64 + lane]);
      float v6 = __half2float(xh[(size_t)s6 * 64 + lane]);
      float v7 = __half2float(xh[(size_t)s7 * 64 + lane]);
      acc += ((v0 + v1) + (v2 + v3)) + ((v4 + v5) + (v6 + v7));
    }
    for (; j + 4 <= dg; j += 4) {
      int s0 = csr[j0 + j], s1 = csr[j0 + j + 1], s2 = csr[j0 + j + 2], s3 = csr[j0 + j + 3];
      float v0 = __half2float(xh[(size_t)s0 * 64 + lane]);
      float v1 = __half2float(xh[(size_t)s1 * 64 + lane]);
      float v2 = __half2float(xh[(size_t)s2 * 64 + lane]);
      float v3 = __half2float(xh[(size_t)s3 * 64 + lane]);
      acc += (v0 + v1) + (v2 + v3);
    }
    for (; j < dg; ++j) {
      int s = csr[j0 + j];
      acc += __half2float(xh[(size_t)s * 64 + lane]);
    }
    Sh[(size_t)n * 64 + lane] = __float2half_rn(acc);
  }
}

// build fp16 B-fragments for the 3 64x64 matrices + c2
// frag f = mat*8 + kk*4 + ct; entry t = lane*8+j holds M[kk*32+(lane>>4)*8+j][ct*16+(lane&15)]
__global__ void k_mats2(const float* __restrict__ We, const float* __restrict__ be,
                        const float* __restrict__ Wn, __half* __restrict__ Wfrag,
                        float* __restrict__ c2) {
  int b = blockIdx.x, t = threadIdx.x;
  if (b < 24) {
    int mat = b >> 3, kk = (b >> 2) & 1, ct = b & 3;
    int lane = t >> 3, j = t & 7;
    int k = kk * 32 + ((lane >> 4) & 3) * 8 + j;
    int col = ct * 16 + (lane & 15);
    float v;
    if (mat == 0) {
      v = Wn[k * 64 + col];
    } else if (mat == 1) {
      float a = 0.f;
      for (int m = 0; m < 64; ++m) a += We[k * 64 + m] * Wn[(64 + m) * 64 + col];
      v = a;
    } else {
      float a = 0.f;
      for (int m = 0; m < 64; ++m) a += We[(64 + k) * 64 + m] * Wn[(64 + m) * 64 + col];
      v = a;
    }
    Wfrag[b * 512 + t] = __float2half_rn(v);
  } else if (t < 64) {
    float a = 0.f;
    for (int m = 0; m < 64; ++m) a += be[m] * Wn[(64 + m) * 64 + t];
    c2[t] = a;
  }
}

// node model via MFMA: h = PReLU(x@M1 + S@M2 + deg*(x@M3 + c2) + b); h -> fp16
// NO stats here — the per-wave atomic tail was the bottleneck (rounds 4-6).
__global__ __launch_bounds__(256) void k_nodeM(const __half* __restrict__ xh,
    const __half* __restrict__ Sh, const int* __restrict__ deg,
    const __half* __restrict__ Wfrag, const float* __restrict__ c2,
    const float* __restrict__ bnode, const float* __restrict__ pa,
    __half* __restrict__ Hh, int N) {
  const f16x8* WF = (const f16x8*)Wfrag;
  int t = threadIdx.x, lane = t & 63;
  f16x8 B[24];
#pragma unroll
  for (int f = 0; f < 24; ++f) B[f] = WF[f * 64 + lane];
  float slope = pa[0];
  int wid = (blockIdx.x * blockDim.x + t) >> 6;
  int nw = (gridDim.x * blockDim.x) >> 6;
  int ntile = N >> 4;
  int r = lane & 15, g = lane >> 4;
  for (int tile = wid; tile < ntile; tile += nw) {
    int n0 = tile << 4;
    float dg[4];
#pragma unroll
    for (int q = 0; q < 4; ++q) dg[q] = (float)deg[n0 + g * 4 + q];
    const f16x8* xp = (const f16x8*)(xh + (size_t)(n0 + r) * 64 + g * 8);
    const f16x8* sp = (const f16x8*)(Sh + (size_t)(n0 + r) * 64 + g * 8);
    f16x8 ax0 = xp[0], ax1 = xp[4];
    f16x8 as0 = sp[0], as1 = sp[4];
    f32x4 accA[4], accB[4];
#pragma unroll
    for (int ct = 0; ct < 4; ++ct) {
      f32x4 a = {0.f, 0.f, 0.f, 0.f};
      a = __builtin_amdgcn_mfma_f32_16x16x32_f16(ax0, B[0 + ct], a, 0, 0, 0);
      a = __builtin_amdgcn_mfma_f32_16x16x32_f16(ax1, B[4 + ct], a, 0, 0, 0);
      a = __builtin_amdgcn_mfma_f32_16x16x32_f16(as0, B[8 + ct], a, 0, 0, 0);
      a = __builtin_amdgcn_mfma_f32_16x16x32_f16(as1, B[12 + ct], a, 0, 0, 0);
      accA[ct] = a;
      f32x4 bb = {0.f, 0.f, 0.f, 0.f};
      bb = __builtin_amdgcn_mfma_f32_16x16x32_f16(ax0, B[16 + ct], bb, 0, 0, 0);
      bb = __builtin_amdgcn_mfma_f32_16x16x32_f16(ax1, B[20 + ct], bb, 0, 0, 0);
      accB[ct] = bb;
    }
#pragma unroll
    for (int ct = 0; ct < 4; ++ct) {
      int c = ct * 16 + r;
      float cc = c2[c], bv = bnode[c];
#pragma unroll
      for (int q = 0; q < 4; ++q) {
        float hv = accA[ct][q] + dg[q] * (accB[ct][q] + cc) + bv;
        hv = hv >= 0.f ? hv : slope * hv;
        Hh[(size_t)(n0 + g * 4 + q) * 64 + c] = __float2half_rn(hv);
      }
    }
  }
}

// column sums/sumsq over Hh: reg accumulate -> LDS atomics -> 128 global atomics/block
__global__ __launch_bounds__(256) void k_stats(const __half2* __restrict__ hh,
    float* __restrict__ stats, int n2) {
  __shared__ float ls[128];
  int t = threadIdx.x;
  if (t < 128) ls[t] = 0.f;
  __syncthreads();
  int cb = (t & 31) * 2;
  float s0 = 0.f, q0 = 0.f, s1 = 0.f, q1 = 0.f;
  int stride = gridDim.x * 256;
  for (int i = blockIdx.x * 256 + t; i < n2; i += stride) {
    __half2 v = hh[i];
    float a = __half2float(v.x), b = __half2float(v.y);
    s0 += a; q0 += a * a;
    s1 += b; q1 += b * b;
  }
  atomicAdd(&ls[cb], s0);
  atomicAdd(&ls[cb + 1], s1);
  atomicAdd(&ls[64 + cb], q0);
  atomicAdd(&ls[64 + cb + 1], q1);
  __syncthreads();
  if (t < 128) atomicAdd(&stats[t], ls[t]);
}

__global__ void k_bnfinal(const float* __restrict__ stats, const float* __restrict__ gamma,
                          const float* __restrict__ beta, float* __restrict__ ss, int N) {
  int o = threadIdx.x;
  if (o < 64) {
    float fn = (float)N;
    float mean = stats[o] / fn;
    float var = stats[64 + o] / fn - mean * mean;
    float inv = rsqrtf(var + 1e-5f);
    float sc = gamma[o] * inv;
    ss[o] = sc;
    ss[64 + o] = beta[o] - mean * sc;
  }
}

__global__ void k_out2(const __half2* __restrict__ hh, const float* __restrict__ ss,
                       float2* __restrict__ out2, int n2) {
  int i = blockIdx.x * blockDim.x + threadIdx.x;
  if (i < n2) {
    int cb = (i & 31) * 2;
    __half2 v = hh[i];
    float2 o;
    o.x = __half2float(v.x) * ss[cb] + ss[64 + cb];
    o.y = __half2float(v.y) * ss[cb + 1] + ss[64 + cb + 1];
    out2[i] = o;
  }
}

// ---------------- launch ----------------

extern "C" void kernel_launch(void* const* d_in, const int* in_sizes, int n_in,
                              void* d_out, int out_size, void* d_ws, size_t ws_size,
                              hipStream_t stream) {
  const float* x     = (const float*)d_in[0];
  const int*   ei    = (const int*)d_in[1];
  const float* We    = (const float*)d_in[2];
  const float* be    = (const float*)d_in[3];
  const float* Wn    = (const float*)d_in[4];
  const float* bnode = (const float*)d_in[5];
  const float* pa    = (const float*)d_in[6];
  const float* gamma = (const float*)d_in[7];
  const float* beta  = (const float*)d_in[8];

  int N = in_sizes[0] / 64;
  int E = in_sizes[1] / 2;
  const int* srcA = ei;
  const int* dstA = ei + E;

  int NBUCK = (N + NPB - 1) / NPB;     // 391

  char* ws = (char*)d_ws;
  size_t off = 0;
  auto alloc = [&](size_t bytes) -> void* {
    void* p = (void*)(ws + off);
    off += (bytes + 255) & ~(size_t)255;
    return p;
  };
  int*    bins   = (int*)alloc((size_t)NBUCK * 4);
  int*    binoff = (int*)alloc((size_t)(NBUCK + 1) * 4);
  int*    cur    = (int*)alloc((size_t)NBUCK * 4);
  int*    packed = (int*)alloc((size_t)E * 4);
  int*    csr    = (int*)alloc((size_t)E * 4);
  int*    offA   = (int*)alloc((size_t)N * 4);
  int*    deg    = (int*)alloc((size_t)N * 4);
  __half* xh     = (__half*)alloc((size_t)N * 64 * 2);
  __half* Sh     = (__half*)alloc((size_t)N * 64 * 2);
  __half* Hh     = (__half*)alloc((size_t)N * 64 * 2);
  __half* Wfrag  = (__half*)alloc((size_t)24 * 512 * 2);
  float*  c2     = (float*)alloc(64 * 4);
  float*  stats  = (float*)alloc(128 * 4);
  float*  ssbuf  = (float*)alloc(128 * 4);

  hipMemsetAsync(bins, 0, (size_t)NBUCK * 4, stream);
  hipMemsetAsync(stats, 0, 128 * 4, stream);

  int FGRID = (E + FCHUNK - 1) / FCHUNK;   // 261
  int n4 = N * 16;
  int vgrid = (n4 + 255) / 256;
  int n2 = N * 32;
  int ntile = N / 16;                       // 6250
  int mgrid = (ntile + 3) / 4;              // 1563 blocks -> 1 tile per wave

  k_hist<<<FGRID, 256, 0, stream>>>(dstA, bins, E, FCHUNK);
  k_scan1<<<1, 1024, 0, stream>>>(bins, binoff, cur, NBUCK, E);
  k_fill3<<<FGRID, 256, 0, stream>>>(srcA, dstA, cur, packed, E);
  k_sort<<<NBUCK, 256, 0, stream>>>(packed, binoff, csr, offA, deg, N);
  k_xhalf<<<vgrid, 256, 0, stream>>>((const float4*)x, (__half2*)xh, n4);
  k_mats2<<<25, 512, 0, stream>>>(We, be, Wn, Wfrag, c2);
  k_agg<<<2048, 256, 0, stream>>>(xh, offA, deg, csr, Sh, N);
  k_nodeM<<<mgrid, 256, 0, stream>>>(xh, Sh, deg, Wfrag, c2, bnode, pa, Hh, N);
  k_stats<<<256, 256, 0, stream>>>((const __half2*)Hh, stats, n2);
  k_bnfinal<<<1, 64, 0, stream>>>(stats, gamma, beta, ssbuf, N);
  k_out2<<<(n2 + 255) / 256, 256, 0, stream>>>((const __half2*)Hh, ssbuf, (float2*)d_out, n2);
}